// Round 11
// baseline (309.085 us; speedup 1.0000x reference)
//
#include <hip/hip_runtime.h>
#include <hip/hip_bf16.h>

using bf16 = __hip_bfloat16;
typedef __fp16 half2_t __attribute__((ext_vector_type(2)));
typedef __fp16 half4_t __attribute__((ext_vector_type(4)));
typedef float  f4_t    __attribute__((ext_vector_type(4)));

#define C1 1.44269504f   // log2(e)
#define C2 2.88539008f   // 2*log2(e)

__device__ __forceinline__ float fexp2(float x) { return __builtin_amdgcn_exp2f(x); }
__device__ __forceinline__ float frcp(float x)  { return __builtin_amdgcn_rcpf(x); }
__device__ __forceinline__ unsigned int f2bfbits(float f) {  // RNE float->bf16 bits
    union { float f; unsigned int u; } c; c.f = f;
    return (c.u + 0x7fffu + ((c.u >> 16) & 1u)) >> 16;
}
__device__ __forceinline__ unsigned int pk2(float a, float b) {
    return f2bfbits(a) | (f2bfbits(b) << 16);
}
__device__ __forceinline__ float blo(unsigned int u) { return __int_as_float((int)(u << 16)); }
__device__ __forceinline__ float bhi(unsigned int u) { return __int_as_float((int)(u & 0xffff0000u)); }

// ws layout (bytes):
//  giRZ uint4[160][64 waves][64 lanes] @ 0          (10,485,760)
//  giN  uint2[160][64][64]            @ 10,485,760  (5,242,880)
//  peRZ uint4[160][64]                @ 15,728,640  (163,840)
//  peN  uint2[160][64]                @ 15,892,480  (81,920)
//  Wca  uint2[160][64]                @ 15,974,400  (81,920)   => 16.06 MB
#define OFF_GIN  10485760
#define OFF_PERZ 15728640
#define OFF_PEN  15892480
#define OFF_WCA  15974400

// ---------------------------------------------------------------
// Kernel 1: encoder + input-gate precompute, MFMA C-operand layout.
// Lane slot L = c + 16*g of wave w=b>>4 holds gate rows 4g..4g+3 of
// chain c = b&15 (bf16 pairs). grid (4,160) x 256.
// ---------------------------------------------------------------
__global__ __launch_bounds__(256) void k_encode(
    const float* __restrict__ x, const float* __restrict__ encW, const float* __restrict__ encb,
    const float* __restrict__ Wih, const float* __restrict__ bih, const float* __restrict__ bhh,
    uint4* __restrict__ giRZ, uint2* __restrict__ giN,
    uint4* __restrict__ peRZ, uint2* __restrict__ peN)
{
    const int k = blockIdx.y, t = threadIdx.x;
    const int b = blockIdx.x * 256 + t;

    __shared__ float sW[144], sbm[12], sWih[432], sbih[36], spet[12], spe3[36];
    if (t < 144) sW[t]  = encW[k * 144 + t];
    if (t < 12)  sbm[t] = encb[k * 12 + t];
    for (int i = t; i < 432; i += 256) sWih[i] = Wih[i];
    if (t < 36)  sbih[t] = bih[t] + (t < 24 ? bhh[t] : 0.f);
    if (t < 12) {
        int m = t >> 1;
        float div = __expf((float)(2 * m) * (-0.7675283643313489f)); // -ln(10000)/12
        float ang = (float)k * div;
        spet[t] = ((t & 1) ? cosf(ang) : sinf(ang)) + sinf((float)k);
    }
    __syncthreads();
    if (t < 12) {
        float sr = 0.f, sz = 0.f, sn = 0.f;
        #pragma unroll
        for (int o = 0; o < 12; o++) {
            sr = fmaf(spet[o], sWih[t * 12 + o], sr);
            sz = fmaf(spet[o], sWih[(12 + t) * 12 + o], sz);
            sn = fmaf(spet[o], sWih[(24 + t) * 12 + o], sn);
        }
        spe3[t] = C1 * sr; spe3[12 + t] = C1 * sz; spe3[24 + t] = C2 * sn;
    }

    const float4* xp = reinterpret_cast<const float4*>(x + (size_t)b * 1920 + k * 12);
    float4 a0 = xp[0], a1 = xp[1], a2 = xp[2];
    float xv[12] = {a0.x,a0.y,a0.z,a0.w, a1.x,a1.y,a1.z,a1.w, a2.x,a2.y,a2.z,a2.w};

    float xs[12];
    #pragma unroll
    for (int o = 0; o < 12; o++) {
        float s = sbm[o];
        #pragma unroll
        for (int i = 0; i < 12; i++) s = fmaf(xv[i], sW[i * 12 + o], s);
        xs[o] = fmaxf(s, 0.f);
    }

    float r12[12], z12[12], n12[12];
    #pragma unroll
    for (int j = 0; j < 12; j++) {
        float sr = sbih[j], sz = sbih[12 + j], sn = sbih[24 + j];
        #pragma unroll
        for (int o = 0; o < 12; o++) {
            sr = fmaf(xs[o], sWih[j * 12 + o], sr);
            sz = fmaf(xs[o], sWih[(12 + j) * 12 + o], sz);
            sn = fmaf(xs[o], sWih[(24 + j) * 12 + o], sn);
        }
        r12[j] = C1 * sr; z12[j] = C1 * sz; n12[j] = C2 * sn;
    }
    __syncthreads();

    if (blockIdx.x == 0 && t < 64) {           // pe in the same per-lane layout
        const int q = t >> 4;
        float vr[4], vz[4], vn[4];
        #pragma unroll
        for (int i = 0; i < 4; i++) {
            int row = 4 * q + i;
            vr[i] = (row < 12) ? spe3[row]      : 0.f;
            vz[i] = (row < 12) ? spe3[12 + row] : 0.f;
            vn[i] = (row < 12) ? spe3[24 + row] : 0.f;
        }
        peRZ[k * 64 + t] = make_uint4(pk2(vr[0],vr[1]), pk2(vr[2],vr[3]),
                                      pk2(vz[0],vz[1]), pk2(vz[2],vz[3]));
        peN [k * 64 + t] = make_uint2(pk2(vn[0],vn[1]), pk2(vn[2],vn[3]));
    }

    const int c = b & 15, w = b >> 4;
    const int base = (k * 64 + w) * 64 + c;
    #pragma unroll
    for (int g = 0; g < 3; g++) {
        giRZ[base + 16 * g] = make_uint4(pk2(r12[4*g], r12[4*g+1]), pk2(r12[4*g+2], r12[4*g+3]),
                                         pk2(z12[4*g], z12[4*g+1]), pk2(z12[4*g+2], z12[4*g+3]));
        giN [base + 16 * g] = make_uint2(pk2(n12[4*g], n12[4*g+1]), pk2(n12[4*g+2], n12[4*g+3]));
    }
}

// ---------------------------------------------------------------
// Kernel 2: two GRU passes as MFMA recurrence + fused decode.
// 64 blocks x 64 (1 wave = 16 chains). h lives as the f16 B-operand;
// D-layout == B-layout for 16x16x16 => zero cross-lane traffic.
// B row 12 == 1.0 (bias lane); gates' gi ride in the C operand.
// GRU2 step k also runs the decode MFMA (A = Wc^T[k]) and stores
// out directly.
// ---------------------------------------------------------------
__global__ __launch_bounds__(64) void k_recur(
    const float* __restrict__ Whh, const float* __restrict__ bhh,
    const uint4* __restrict__ giRZ, const uint2* __restrict__ giN,
    const uint4* __restrict__ peRZ, const uint2* __restrict__ peN,
    const uint2* __restrict__ Wca, float* __restrict__ out)
{
    const int lane = threadIdx.x;
    const int c = lane & 15, q = lane >> 4;
    const int wv = blockIdx.x;

    // A operands (constant all steps): A_g[m=c][kd=4q+i]
    union HU { half4_t h; half2_t p[2]; uint2 u; };
    half4_t Ar, Az, An;
    {
        float vr[4], vz[4], vn[4];
        #pragma unroll
        for (int i = 0; i < 4; i++) {
            int kd = 4 * q + i;
            float fr = 0.f, fz = 0.f, fn = 0.f;
            if (c < 12) {
                if (kd < 12) {
                    fr = C1 * Whh[c * 12 + kd];
                    fz = C1 * Whh[(12 + c) * 12 + kd];
                    fn = C2 * Whh[(24 + c) * 12 + kd];
                } else if (kd == 12) {
                    fn = C2 * bhh[24 + c];
                }
            }
            vr[i] = fr; vz[i] = fz; vn[i] = fn;
        }
        HU ur, uz, un;
        ur.p[0] = __builtin_amdgcn_cvt_pkrtz(vr[0], vr[1]);
        ur.p[1] = __builtin_amdgcn_cvt_pkrtz(vr[2], vr[3]);
        uz.p[0] = __builtin_amdgcn_cvt_pkrtz(vz[0], vz[1]);
        uz.p[1] = __builtin_amdgcn_cvt_pkrtz(vz[2], vz[3]);
        un.p[0] = __builtin_amdgcn_cvt_pkrtz(vn[0], vn[1]);
        un.p[1] = __builtin_amdgcn_cvt_pkrtz(vn[2], vn[3]);
        Ar = ur.h; Az = uz.h; An = un.h;
    }

    // B state: h (f16). Lanes q==3 hold the constant {1,0,0,0} (k=12 bias row).
    HU B;
    B.u.x = (q < 3) ? 0u : 0x3C00u;
    B.u.y = 0u;

    float hsf[4] = {0.f, 0.f, 0.f, 0.f};
    float pp [4] = {1.f, 1.f, 1.f, 1.f};
    const f4_t zero4 = {0.f, 0.f, 0.f, 0.f};

    uint4 gRZ[4]; uint2 gN[4];
    #pragma unroll
    for (int i = 0; i < 4; i++) {
        gRZ[i] = giRZ[(i * 64 + wv) * 64 + lane];
        gN [i] = giN [(i * 64 + wv) * 64 + lane];
    }

    // ---- GRU1 ----
    for (int ko = 0; ko < 160; ko += 4) {
        #pragma unroll
        for (int i = 0; i < 4; i++) {
            const int k = ko + i;
            const int kp = (k + 4 > 159) ? 159 : k + 4;
            f4_t Cr = {blo(gRZ[i].x), bhi(gRZ[i].x), blo(gRZ[i].y), bhi(gRZ[i].y)};
            f4_t Cz = {blo(gRZ[i].z), bhi(gRZ[i].z), blo(gRZ[i].w), bhi(gRZ[i].w)};
            float Gn[4] = {blo(gN[i].x), bhi(gN[i].x), blo(gN[i].y), bhi(gN[i].y)};
            gRZ[i] = giRZ[(kp * 64 + wv) * 64 + lane];
            gN [i] = giN [(kp * 64 + wv) * 64 + lane];
            f4_t Dr = __builtin_amdgcn_mfma_f32_16x16x16f16(Ar, B.h, Cr, 0, 0, 0);
            f4_t Dz = __builtin_amdgcn_mfma_f32_16x16x16f16(Az, B.h, Cz, 0, 0, 0);
            f4_t Dn = __builtin_amdgcn_mfma_f32_16x16x16f16(An, B.h, zero4, 0, 0, 0);
            #pragma unroll
            for (int ii = 0; ii < 4; ii++) {
                float r  = frcp(1.f + fexp2(-Dr[ii]));
                float w  = frcp(1.f + fexp2(Dz[ii]));
                float tt = fmaf(r, Dn[ii], Gn[ii]);
                float e  = frcp(1.f + fexp2(tt));
                float s  = fmaf(-2.f, e, pp[ii]);
                float hj = fmaf(w, s, hsf[ii]);
                hsf[ii] = hj; pp[ii] = 1.f - hj;
            }
            HU nb;
            nb.p[0] = __builtin_amdgcn_cvt_pkrtz(hsf[0], hsf[1]);
            nb.p[1] = __builtin_amdgcn_cvt_pkrtz(hsf[2], hsf[3]);
            B.u.x = (q < 3) ? nb.u.x : 0x3C00u;
            B.u.y = (q < 3) ? nb.u.y : 0u;
        }
    }

    // ---- GRU2 + fused decode ----
    uint4 pRZ[4]; uint2 pN[4]; uint2 wc[4];
    #pragma unroll
    for (int i = 0; i < 4; i++) {
        gRZ[i] = giRZ[(i * 64 + wv) * 64 + lane];
        gN [i] = giN [(i * 64 + wv) * 64 + lane];
        pRZ[i] = peRZ[i * 64 + lane];
        pN [i] = peN [i * 64 + lane];
        wc [i] = Wca [i * 64 + lane];
    }
    float* orow = out + ((size_t)wv * 16 + c) * 1920 + 4 * q;
    for (int ko = 0; ko < 160; ko += 4) {
        #pragma unroll
        for (int i = 0; i < 4; i++) {
            const int k = ko + i;
            const int kp = (k + 4 > 159) ? 159 : k + 4;
            f4_t Cr = {blo(gRZ[i].x) + blo(pRZ[i].x), bhi(gRZ[i].x) + bhi(pRZ[i].x),
                       blo(gRZ[i].y) + blo(pRZ[i].y), bhi(gRZ[i].y) + bhi(pRZ[i].y)};
            f4_t Cz = {blo(gRZ[i].z) + blo(pRZ[i].z), bhi(gRZ[i].z) + bhi(pRZ[i].z),
                       blo(gRZ[i].w) + blo(pRZ[i].w), bhi(gRZ[i].w) + bhi(pRZ[i].w)};
            float Gn[4] = {blo(gN[i].x) + blo(pN[i].x), bhi(gN[i].x) + bhi(pN[i].x),
                           blo(gN[i].y) + blo(pN[i].y), bhi(gN[i].y) + bhi(pN[i].y)};
            HU adec; adec.u = wc[i];
            gRZ[i] = giRZ[(kp * 64 + wv) * 64 + lane];
            gN [i] = giN [(kp * 64 + wv) * 64 + lane];
            pRZ[i] = peRZ[kp * 64 + lane];
            pN [i] = peN [kp * 64 + lane];
            wc [i] = Wca [kp * 64 + lane];
            f4_t Dr = __builtin_amdgcn_mfma_f32_16x16x16f16(Ar, B.h, Cr, 0, 0, 0);
            f4_t Dz = __builtin_amdgcn_mfma_f32_16x16x16f16(Az, B.h, Cz, 0, 0, 0);
            f4_t Dn = __builtin_amdgcn_mfma_f32_16x16x16f16(An, B.h, zero4, 0, 0, 0);
            #pragma unroll
            for (int ii = 0; ii < 4; ii++) {
                float r  = frcp(1.f + fexp2(-Dr[ii]));
                float w  = frcp(1.f + fexp2(Dz[ii]));
                float tt = fmaf(r, Dn[ii], Gn[ii]);
                float e  = frcp(1.f + fexp2(tt));
                float s  = fmaf(-2.f, e, pp[ii]);
                float hj = fmaf(w, s, hsf[ii]);
                hsf[ii] = hj; pp[ii] = 1.f - hj;
            }
            HU nb;
            nb.p[0] = __builtin_amdgcn_cvt_pkrtz(hsf[0], hsf[1]);
            nb.p[1] = __builtin_amdgcn_cvt_pkrtz(hsf[2], hsf[3]);
            B.u.x = (q < 3) ? nb.u.x : 0x3C00u;
            B.u.y = (q < 3) ? nb.u.y : 0u;
            f4_t O = __builtin_amdgcn_mfma_f32_16x16x16f16(adec.h, B.h, zero4, 0, 0, 0);
            if (q < 3) {
                float4* op = reinterpret_cast<float4*>(orow + k * 12);
                *op = make_float4(O[0], O[1], O[2], O[3]);
            }
        }
    }
}

// ---------------------------------------------------------------
// Kernel 3: fold Wc = W1@W2 (+bc) per k, emit as f16 MFMA A-operand
// Wca[k][lane]: A[m=o=lane&15][kd=4*(lane>>4)+i]; kd==12 -> bc.
// grid 160 x 256.
// ---------------------------------------------------------------
__global__ __launch_bounds__(256) void k_fold(
    const float* __restrict__ W1, const float* __restrict__ b1,
    const float* __restrict__ W2, const float* __restrict__ b2,
    uint2* __restrict__ Wca)
{
    const int k = blockIdx.x, t = threadIdx.x;
    __shared__ float sB[12288];   // W2[k], [h][12]
    __shared__ float sb1[1024];
    __shared__ float sWc[144], sbc[12];
    {
        const float4* w2p = reinterpret_cast<const float4*>(W2 + (size_t)k * 12288);
        float4* sB4 = reinterpret_cast<float4*>(sB);
        for (int i = t; i < 3072; i += 256) sB4[i] = w2p[i];
        const float4* b1p = reinterpret_cast<const float4*>(b1 + (size_t)k * 1024);
        float4* sb14 = reinterpret_cast<float4*>(sb1);
        sb14[t] = b1p[t];
    }
    __syncthreads();
    if (t < 156) {
        const int o = (t < 144) ? (t % 12) : (t - 144);
        float s0 = 0.f, s1 = 0.f, s2 = 0.f, s3 = 0.f;
        if (t < 144) {
            const float4* va4 = reinterpret_cast<const float4*>(W1 + (size_t)k * 12288 + (size_t)(t / 12) * 1024);
            #pragma unroll 4
            for (int qq = 0; qq < 256; qq++) {
                float4 a = va4[qq];
                const float* bq = sB + qq * 48 + o;
                s0 = fmaf(a.x, bq[0],  s0);
                s1 = fmaf(a.y, bq[12], s1);
                s2 = fmaf(a.z, bq[24], s2);
                s3 = fmaf(a.w, bq[36], s3);
            }
        } else {
            #pragma unroll 4
            for (int hh = 0; hh < 1024; hh += 4) {
                const float* bq = sB + hh * 12 + o;
                s0 = fmaf(sb1[hh],     bq[0],  s0);
                s1 = fmaf(sb1[hh + 1], bq[12], s1);
                s2 = fmaf(sb1[hh + 2], bq[24], s2);
                s3 = fmaf(sb1[hh + 3], bq[36], s3);
            }
        }
        float s = (s0 + s1) + (s2 + s3);
        if (t < 144) sWc[t] = s;
        else         sbc[t - 144] = s + b2[k * 12 + o];
    }
    __syncthreads();
    if (t < 64) {
        const int o = t & 15, q = t >> 4;
        float v[4];
        #pragma unroll
        for (int i = 0; i < 4; i++) {
            int kd = 4 * q + i;
            float f = 0.f;
            if (o < 12) {
                if (kd < 12)       f = sWc[kd * 12 + o];
                else if (kd == 12) f = sbc[o];
            }
            v[i] = f;
        }
        union { half2_t p[2]; uint2 u; } pk;
        pk.p[0] = __builtin_amdgcn_cvt_pkrtz(v[0], v[1]);
        pk.p[1] = __builtin_amdgcn_cvt_pkrtz(v[2], v[3]);
        Wca[k * 64 + t] = pk.u;
    }
}

// ---------------------------------------------------------------
extern "C" void kernel_launch(void* const* d_in, const int* in_sizes, int n_in,
                              void* d_out, int out_size, void* d_ws, size_t ws_size,
                              hipStream_t stream)
{
    const float* x    = (const float*)d_in[0];
    const float* encW = (const float*)d_in[1];
    const float* encb = (const float*)d_in[2];
    const float* Wih  = (const float*)d_in[3];
    const float* Whh  = (const float*)d_in[4];
    const float* bih  = (const float*)d_in[5];
    const float* bhh  = (const float*)d_in[6];
    const float* W1   = (const float*)d_in[7];
    const float* b1   = (const float*)d_in[8];
    const float* W2   = (const float*)d_in[9];
    const float* b2   = (const float*)d_in[10];
    float* out = (float*)d_out;

    char* ws = (char*)d_ws;
    uint4* giRZ = (uint4*)(ws);
    uint2* giN  = (uint2*)(ws + OFF_GIN);
    uint4* peRZ = (uint4*)(ws + OFF_PERZ);
    uint2* peN  = (uint2*)(ws + OFF_PEN);
    uint2* Wca  = (uint2*)(ws + OFF_WCA);

    k_encode<<<dim3(4, 160), 256, 0, stream>>>(x, encW, encb, Wih, bih, bhh, giRZ, giN, peRZ, peN);
    k_fold  <<<dim3(160),    256, 0, stream>>>(W1, b1, W2, b2, Wca);
    k_recur <<<dim3(64),     64,  0, stream>>>(Whh, bhh, giRZ, giN, peRZ, peN, Wca, out);
}

// Round 12
// 205.110 us; speedup vs baseline: 1.5069x; 1.5069x over previous
//
#include <hip/hip_runtime.h>
#include <hip/hip_bf16.h>

using bf16 = __hip_bfloat16;
typedef __fp16 h2v __attribute__((ext_vector_type(2)));
typedef float  v2f __attribute__((ext_vector_type(2)));

#define C1 1.44269504f   // log2(e)
#define C2 2.88539008f   // 2*log2(e)

__device__ __forceinline__ float fexp2(float x) { return __builtin_amdgcn_exp2f(x); }
__device__ __forceinline__ float frcp(float x)  { return __builtin_amdgcn_rcpf(x); }

__device__ __forceinline__ unsigned int f2bfbits(float f) {  // RNE float->bf16 bits
    union { float f; unsigned int u; } c; c.f = f;
    return (c.u + 0x7fffu + ((c.u >> 16) & 1u)) >> 16;
}
__device__ __forceinline__ float blo(unsigned int u) { return __int_as_float((int)(u << 16)); }
__device__ __forceinline__ float bhi(unsigned int u) { return __int_as_float((int)(u & 0xffff0000u)); }

union HU { h2v h; unsigned int u; };

#if __has_builtin(__builtin_amdgcn_fdot2)
#define HAVE_FDOT2 1
#else
#define HAVE_FDOT2 0
#endif

// gi layout: [k][b][12] of uint2 {lo = r|z<<16, hi = n} (bf16 bits, pre-scaled C1/C1/C2)
#define KSTR 12288   // uint2 per k-slice (1024*12)
// ws: gi @0 (15,728,640 B) | pegi float4[160][12] @15,728,640 (30,720 B) => 15.76 MB
#define OFF_PEGI 15728640

// ---------------------------------------------------------------
// Kernel 1: encoder + input-gate precompute. grid (4,160) x 256.
// (byte-identical to r8 — proven)
// ---------------------------------------------------------------
__global__ __launch_bounds__(256) void k_encode(
    const float* __restrict__ x, const float* __restrict__ encW, const float* __restrict__ encb,
    const float* __restrict__ Wih, const float* __restrict__ bih, const float* __restrict__ bhh,
    uint2* __restrict__ gi, float4* __restrict__ pegi)
{
    const int k = blockIdx.y, t = threadIdx.x;
    const int b = blockIdx.x * 256 + t;

    __shared__ float sW[144], sbm[12], sWih[432], sbih[36], spet[12];
    __shared__ uint2 st[256 * 13];          // 26 KB staging, stride 13
    if (t < 144) sW[t]  = encW[k * 144 + t];
    if (t < 12)  sbm[t] = encb[k * 12 + t];
    for (int i = t; i < 432; i += 256) sWih[i] = Wih[i];
    if (t < 36)  sbih[t] = bih[t] + (t < 24 ? bhh[t] : 0.f);
    if (t < 12) {
        int m = t >> 1;
        float div = __expf((float)(2 * m) * (-0.7675283643313489f)); // -ln(10000)/12
        float ang = (float)k * div;
        spet[t] = ((t & 1) ? cosf(ang) : sinf(ang)) + sinf((float)k);
    }
    __syncthreads();
    if (t < 12 && blockIdx.x == 0) {
        float sr = 0.f, sz = 0.f, sn = 0.f;
        #pragma unroll
        for (int o = 0; o < 12; o++) {
            sr = fmaf(spet[o], sWih[t * 12 + o], sr);
            sz = fmaf(spet[o], sWih[(12 + t) * 12 + o], sz);
            sn = fmaf(spet[o], sWih[(24 + t) * 12 + o], sn);
        }
        pegi[k * 12 + t] = make_float4(C1 * sr, C1 * sz, C2 * sn, 0.f);
    }

    const float4* xp = reinterpret_cast<const float4*>(x + (size_t)b * 1920 + k * 12);
    float4 a0 = xp[0], a1 = xp[1], a2 = xp[2];
    float xv[12] = {a0.x,a0.y,a0.z,a0.w, a1.x,a1.y,a1.z,a1.w, a2.x,a2.y,a2.z,a2.w};

    float xs[12];
    #pragma unroll
    for (int o = 0; o < 12; o++) {
        float s = sbm[o];
        #pragma unroll
        for (int i = 0; i < 12; i++) s = fmaf(xv[i], sW[i * 12 + o], s);
        xs[o] = fmaxf(s, 0.f);
    }

    #pragma unroll
    for (int j = 0; j < 12; j++) {
        float sr = sbih[j], sz = sbih[12 + j], sn = sbih[24 + j];
        #pragma unroll
        for (int o = 0; o < 12; o++) {
            sr = fmaf(xs[o], sWih[j * 12 + o], sr);
            sz = fmaf(xs[o], sWih[(12 + j) * 12 + o], sz);
            sn = fmaf(xs[o], sWih[(24 + j) * 12 + o], sn);
        }
        st[t * 13 + j] = make_uint2(f2bfbits(C1 * sr) | (f2bfbits(C1 * sz) << 16),
                                    f2bfbits(C2 * sn));
    }
    __syncthreads();
    uint2* gbase = gi + (size_t)k * KSTR + (size_t)blockIdx.x * 3072;
    for (int i = t; i < 3072; i += 256) {
        int bl = i / 12;
        gbase[i] = st[bl * 13 + (i - bl * 12)];
    }
}

// ---------------------------------------------------------------
// Kernel 2: two GRU passes — SGPR-h + v_dot2_f32_f16 dots.
// One chain per wave (1024 blocks x 64); lane j<12 owns unit j.
// hj -> f16 bits (cvt_pkrtz) -> 12 readlanes -> 6 wave-uniform
// packed halves assembled on the SALU pipe -> fdot2 src operands.
// 2-way tree per gate. Depth-8 gi prefetch.
// ---------------------------------------------------------------
__global__ __launch_bounds__(64) void k_recur(
    const float* __restrict__ Whh, const float* __restrict__ bhh,
    const uint2* __restrict__ gi, const float4* __restrict__ pegi,
    float* __restrict__ hout)
{
    const int lane = threadIdx.x;
    const int ju = (lane < 12) ? lane : 11;
    const int b = blockIdx.x;

#if HAVE_FDOT2
    HU wr[6], wz[6], wn[6];
    #pragma unroll
    for (int i = 0; i < 6; i++) {
        wr[i].h = __builtin_amdgcn_cvt_pkrtz(C1 * Whh[ju * 12 + 2*i],        C1 * Whh[ju * 12 + 2*i + 1]);
        wz[i].h = __builtin_amdgcn_cvt_pkrtz(C1 * Whh[(12 + ju) * 12 + 2*i], C1 * Whh[(12 + ju) * 12 + 2*i + 1]);
        wn[i].h = __builtin_amdgcn_cvt_pkrtz(C2 * Whh[(24 + ju) * 12 + 2*i], C2 * Whh[(24 + ju) * 12 + 2*i + 1]);
    }
    unsigned int hp[6];
    #pragma unroll
    for (int i = 0; i < 6; i++) hp[i] = 0u;
#else
    v2f wr2[6], wz2[6], wn2[6];
    #pragma unroll
    for (int i = 0; i < 6; i++) {
        wr2[i] = (v2f){C1 * Whh[ju * 12 + 2*i],        C1 * Whh[ju * 12 + 2*i + 1]};
        wz2[i] = (v2f){C1 * Whh[(12 + ju) * 12 + 2*i], C1 * Whh[(12 + ju) * 12 + 2*i + 1]};
        wn2[i] = (v2f){C2 * Whh[(24 + ju) * 12 + 2*i], C2 * Whh[(24 + ju) * 12 + 2*i + 1]};
    }
    v2f hs2[6];
    #pragma unroll
    for (int i = 0; i < 6; i++) hs2[i] = (v2f){0.f, 0.f};
#endif
    const float bn = C2 * bhh[24 + ju];

    const uint2* gp = gi + (size_t)b * 12 + ju;
    float hself = 0.f, p = 1.f;         // p = 1 - hself

    uint2 buf[8];
    #pragma unroll
    for (int i = 0; i < 8; i++) buf[i] = gp[(size_t)i * KSTR];

    // ---- GRU1 (only final h needed) ----
    for (int ko = 0; ko < 160; ko += 8) {
        #pragma unroll
        for (int i = 0; i < 8; i++) {
            const int k = ko + i;
            const int kp = (k + 8 > 159) ? 159 : k + 8;
            float gr = blo(buf[i].x);
            float gz = bhi(buf[i].x);
            float gn = blo(buf[i].y);
            buf[i] = gp[(size_t)kp * KSTR];
#if HAVE_FDOT2
            HU h0, h1, h2c, h3, h4, h5;
            h0.u = hp[0]; h1.u = hp[1]; h2c.u = hp[2]; h3.u = hp[3]; h4.u = hp[4]; h5.u = hp[5];
            float r0 = __builtin_amdgcn_fdot2(wr[0].h, h0.h, gr, false);
            r0 = __builtin_amdgcn_fdot2(wr[1].h, h1.h, r0, false);
            r0 = __builtin_amdgcn_fdot2(wr[2].h, h2c.h, r0, false);
            float r1 = __builtin_amdgcn_fdot2(wr[3].h, h3.h, 0.f, false);
            r1 = __builtin_amdgcn_fdot2(wr[4].h, h4.h, r1, false);
            r1 = __builtin_amdgcn_fdot2(wr[5].h, h5.h, r1, false);
            float hr = r0 + r1;
            float n0 = __builtin_amdgcn_fdot2(wn[0].h, h0.h, bn, false);
            n0 = __builtin_amdgcn_fdot2(wn[1].h, h1.h, n0, false);
            n0 = __builtin_amdgcn_fdot2(wn[2].h, h2c.h, n0, false);
            float n1 = __builtin_amdgcn_fdot2(wn[3].h, h3.h, 0.f, false);
            n1 = __builtin_amdgcn_fdot2(wn[4].h, h4.h, n1, false);
            n1 = __builtin_amdgcn_fdot2(wn[5].h, h5.h, n1, false);
            float hn = n0 + n1;
            float z0 = __builtin_amdgcn_fdot2(wz[0].h, h0.h, gz, false);
            z0 = __builtin_amdgcn_fdot2(wz[1].h, h1.h, z0, false);
            z0 = __builtin_amdgcn_fdot2(wz[2].h, h2c.h, z0, false);
            float z1 = __builtin_amdgcn_fdot2(wz[3].h, h3.h, 0.f, false);
            z1 = __builtin_amdgcn_fdot2(wz[4].h, h4.h, z1, false);
            z1 = __builtin_amdgcn_fdot2(wz[5].h, h5.h, z1, false);
            float hz = z0 + z1;
#else
            v2f ar = (v2f){gr, 0.f}, az = (v2f){gz, 0.f}, an = (v2f){bn, 0.f};
            #pragma unroll
            for (int d = 0; d < 6; d++) { an += wn2[d] * hs2[d]; ar += wr2[d] * hs2[d]; az += wz2[d] * hs2[d]; }
            float hr = ar.x + ar.y, hz = az.x + az.y, hn = an.x + an.y;
#endif
            float r = frcp(1.f + fexp2(-hr));
            float w = frcp(1.f + fexp2(hz));        // 1 - z
            float t = fmaf(r, hn, gn);
            float e = frcp(1.f + fexp2(t));         // n = 1 - 2e
            float hj = fmaf(w, fmaf(-2.f, e, p), hself); // h + w*((1-h) - 2e)
            hself = hj; p = 1.f - hj;
#if HAVE_FDOT2
            HU hb; hb.h = __builtin_amdgcn_cvt_pkrtz(hj, hj);
            #pragma unroll
            for (int d = 0; d < 6; d++) {
                unsigned int lo = (unsigned int)__builtin_amdgcn_readlane((int)hb.u, 2*d);
                unsigned int hi = (unsigned int)__builtin_amdgcn_readlane((int)hb.u, 2*d + 1);
                hp[d] = (lo & 0xffffu) | (hi << 16);
            }
#else
            int hv = __float_as_int(hj);
            #pragma unroll
            for (int d = 0; d < 6; d++)
                hs2[d] = (v2f){__int_as_float(__builtin_amdgcn_readlane(hv, 2*d)),
                               __int_as_float(__builtin_amdgcn_readlane(hv, 2*d + 1))};
#endif
        }
    }

    // ---- GRU2 (emit h every step); gi2 = gi1 + pegi[k] ----
    const float4* pp = pegi + ju;
    float4 pb[8];
    #pragma unroll
    for (int i = 0; i < 8; i++) {
        buf[i] = gp[(size_t)i * KSTR];
        pb[i]  = pp[i * 12];
    }
    float* ho = hout + (size_t)b * 1920;            // [b][k][12]
    for (int ko = 0; ko < 160; ko += 8) {
        #pragma unroll
        for (int i = 0; i < 8; i++) {
            const int k = ko + i;
            const int kp = (k + 8 > 159) ? 159 : k + 8;
            float gr = blo(buf[i].x) + pb[i].x;
            float gz = bhi(buf[i].x) + pb[i].y;
            float gn = blo(buf[i].y) + pb[i].z;
            buf[i] = gp[(size_t)kp * KSTR];
            pb[i]  = pp[kp * 12];
#if HAVE_FDOT2
            HU h0, h1, h2c, h3, h4, h5;
            h0.u = hp[0]; h1.u = hp[1]; h2c.u = hp[2]; h3.u = hp[3]; h4.u = hp[4]; h5.u = hp[5];
            float r0 = __builtin_amdgcn_fdot2(wr[0].h, h0.h, gr, false);
            r0 = __builtin_amdgcn_fdot2(wr[1].h, h1.h, r0, false);
            r0 = __builtin_amdgcn_fdot2(wr[2].h, h2c.h, r0, false);
            float r1 = __builtin_amdgcn_fdot2(wr[3].h, h3.h, 0.f, false);
            r1 = __builtin_amdgcn_fdot2(wr[4].h, h4.h, r1, false);
            r1 = __builtin_amdgcn_fdot2(wr[5].h, h5.h, r1, false);
            float hr = r0 + r1;
            float n0 = __builtin_amdgcn_fdot2(wn[0].h, h0.h, bn, false);
            n0 = __builtin_amdgcn_fdot2(wn[1].h, h1.h, n0, false);
            n0 = __builtin_amdgcn_fdot2(wn[2].h, h2c.h, n0, false);
            float n1 = __builtin_amdgcn_fdot2(wn[3].h, h3.h, 0.f, false);
            n1 = __builtin_amdgcn_fdot2(wn[4].h, h4.h, n1, false);
            n1 = __builtin_amdgcn_fdot2(wn[5].h, h5.h, n1, false);
            float hn = n0 + n1;
            float z0 = __builtin_amdgcn_fdot2(wz[0].h, h0.h, gz, false);
            z0 = __builtin_amdgcn_fdot2(wz[1].h, h1.h, z0, false);
            z0 = __builtin_amdgcn_fdot2(wz[2].h, h2c.h, z0, false);
            float z1 = __builtin_amdgcn_fdot2(wz[3].h, h3.h, 0.f, false);
            z1 = __builtin_amdgcn_fdot2(wz[4].h, h4.h, z1, false);
            z1 = __builtin_amdgcn_fdot2(wz[5].h, h5.h, z1, false);
            float hz = z0 + z1;
#else
            v2f ar = (v2f){gr, 0.f}, az = (v2f){gz, 0.f}, an = (v2f){bn, 0.f};
            #pragma unroll
            for (int d = 0; d < 6; d++) { an += wn2[d] * hs2[d]; ar += wr2[d] * hs2[d]; az += wz2[d] * hs2[d]; }
            float hr = ar.x + ar.y, hz = az.x + az.y, hn = an.x + an.y;
#endif
            float r = frcp(1.f + fexp2(-hr));
            float w = frcp(1.f + fexp2(hz));
            float t = fmaf(r, hn, gn);
            float e = frcp(1.f + fexp2(t));
            float hj = fmaf(w, fmaf(-2.f, e, p), hself);
            hself = hj; p = 1.f - hj;
            if (lane < 12) ho[k * 12 + lane] = hj;
#if HAVE_FDOT2
            HU hb; hb.h = __builtin_amdgcn_cvt_pkrtz(hj, hj);
            #pragma unroll
            for (int d = 0; d < 6; d++) {
                unsigned int lo = (unsigned int)__builtin_amdgcn_readlane((int)hb.u, 2*d);
                unsigned int hi = (unsigned int)__builtin_amdgcn_readlane((int)hb.u, 2*d + 1);
                hp[d] = (lo & 0xffffu) | (hi << 16);
            }
#else
            int hv = __float_as_int(hj);
            #pragma unroll
            for (int d = 0; d < 6; d++)
                hs2[d] = (v2f){__int_as_float(__builtin_amdgcn_readlane(hv, 2*d)),
                               __int_as_float(__builtin_amdgcn_readlane(hv, 2*d + 1))};
#endif
        }
    }
}

// ---------------------------------------------------------------
// Kernel 3: fold + apply merged (byte-identical to r8 — proven).
// grid 160 x 256.
// ---------------------------------------------------------------
__global__ __launch_bounds__(256) void k_foldapply(
    const float* __restrict__ W1, const float* __restrict__ b1,
    const float* __restrict__ W2, const float* __restrict__ b2,
    float* __restrict__ out)
{
    const int k = blockIdx.x, t = threadIdx.x;
    __shared__ float sB[12288];   // W2[k], [h][12]
    __shared__ float sb1[1024];
    __shared__ float sWc[144], sbc[12];
    {
        const float4* w2p = reinterpret_cast<const float4*>(W2 + (size_t)k * 12288);
        float4* sB4 = reinterpret_cast<float4*>(sB);
        for (int i = t; i < 3072; i += 256) sB4[i] = w2p[i];
        const float4* b1p = reinterpret_cast<const float4*>(b1 + (size_t)k * 1024);
        float4* sb14 = reinterpret_cast<float4*>(sb1);
        sb14[t] = b1p[t];
    }
    __syncthreads();
    if (t < 156) {
        const int o = (t < 144) ? (t % 12) : (t - 144);
        float s0 = 0.f, s1 = 0.f, s2 = 0.f, s3 = 0.f;
        if (t < 144) {
            const float4* va4 = reinterpret_cast<const float4*>(W1 + (size_t)k * 12288 + (size_t)(t / 12) * 1024);
            #pragma unroll 4
            for (int q = 0; q < 256; q++) {
                float4 a = va4[q];
                const float* bq = sB + q * 48 + o;
                s0 = fmaf(a.x, bq[0],  s0);
                s1 = fmaf(a.y, bq[12], s1);
                s2 = fmaf(a.z, bq[24], s2);
                s3 = fmaf(a.w, bq[36], s3);
            }
        } else {
            #pragma unroll 4
            for (int hh = 0; hh < 1024; hh += 4) {
                const float* bq = sB + hh * 12 + o;
                s0 = fmaf(sb1[hh],     bq[0],  s0);
                s1 = fmaf(sb1[hh + 1], bq[12], s1);
                s2 = fmaf(sb1[hh + 2], bq[24], s2);
                s3 = fmaf(sb1[hh + 3], bq[36], s3);
            }
        }
        float s = (s0 + s1) + (s2 + s3);
        if (t < 144) sWc[t] = s;
        else         sbc[t - 144] = s + b2[k * 12 + o];
    }
    __syncthreads();

    for (int bb = t; bb < 1024; bb += 256) {
        float* hp = out + (size_t)bb * 1920 + k * 12;
        float4* h4 = reinterpret_cast<float4*>(hp);
        float4 a0 = h4[0], a1 = h4[1], a2 = h4[2];
        float hv[12] = {a0.x,a0.y,a0.z,a0.w, a1.x,a1.y,a1.z,a1.w, a2.x,a2.y,a2.z,a2.w};
        float ov[12];
        #pragma unroll
        for (int o = 0; o < 12; o++) {
            float s = sbc[o];
            #pragma unroll
            for (int d = 0; d < 12; d++) s = fmaf(hv[d], sWc[d * 12 + o], s);
            ov[o] = s;
        }
        h4[0] = make_float4(ov[0], ov[1], ov[2],  ov[3]);
        h4[1] = make_float4(ov[4], ov[5], ov[6],  ov[7]);
        h4[2] = make_float4(ov[8], ov[9], ov[10], ov[11]);
    }
}

// ---------------------------------------------------------------
extern "C" void kernel_launch(void* const* d_in, const int* in_sizes, int n_in,
                              void* d_out, int out_size, void* d_ws, size_t ws_size,
                              hipStream_t stream)
{
    const float* x    = (const float*)d_in[0];
    const float* encW = (const float*)d_in[1];
    const float* encb = (const float*)d_in[2];
    const float* Wih  = (const float*)d_in[3];
    const float* Whh  = (const float*)d_in[4];
    const float* bih  = (const float*)d_in[5];
    const float* bhh  = (const float*)d_in[6];
    const float* W1   = (const float*)d_in[7];
    const float* b1   = (const float*)d_in[8];
    const float* W2   = (const float*)d_in[9];
    const float* b2   = (const float*)d_in[10];
    float* out = (float*)d_out;

    char* ws = (char*)d_ws;
    uint2*  gi   = (uint2*)(ws);
    float4* pegi = (float4*)(ws + OFF_PEGI);

    k_encode   <<<dim3(4, 160), 256, 0, stream>>>(x, encW, encb, Wih, bih, bhh, gi, pegi);
    k_recur    <<<dim3(1024),   64,  0, stream>>>(Whh, bhh, gi, pegi, out);
    k_foldapply<<<dim3(160),    256, 0, stream>>>(W1, b1, W2, b2, out);
}